// Round 8
// baseline (608.214 us; speedup 1.0000x reference)
//
#include <hip/hip_runtime.h>
#include <hip/hip_bf16.h>
#include <math.h>

#define PI_F 3.14159265358979323846f

typedef unsigned short u16;
typedef unsigned int   u32;
typedef float    f32x4 __attribute__((ext_vector_type(4)));
typedef _Float16 f16x8 __attribute__((ext_vector_type(8)));
typedef u16      u16x8 __attribute__((ext_vector_type(8)));
typedef u16      u16x4 __attribute__((ext_vector_type(4)));

__device__ __forceinline__ u16 f2h(float f){ union{ _Float16 h; u16 u; } c; c.h = (_Float16)f; return c.u; }
__device__ __forceinline__ float h2f(u16 u){ union{ u16 u; _Float16 h; } c; c.u = u; return (float)c.h; }

__device__ __forceinline__ void gl16(const void* g, void* l){
  __builtin_amdgcn_global_load_lds((const __attribute__((address_space(1))) u32*)g,
                                   (__attribute__((address_space(3))) u32*)l, 16, 0, 0);
}

__device__ __forceinline__ int SWZ(int r){ return (r>>1)&3; }

__device__ __forceinline__ float wred_max(float v){
#pragma unroll
  for (int m = 32; m; m >>= 1) v = fmaxf(v, __shfl_xor(v, m));
  return v;
}
__device__ __forceinline__ float wred_min(float v){
#pragma unroll
  for (int m = 32; m; m >>= 1) v = fminf(v, __shfl_xor(v, m));
  return v;
}
__device__ __forceinline__ float wred_sum(float v){
#pragma unroll
  for (int m = 32; m; m >>= 1) v += __shfl_xor(v, m);
  return v;
}

__device__ __forceinline__ float ssslu_f(float x, float shp, float bp1){
  float s = x / (1.0f + fabsf(x));
  return x * (__sinf(s * shp) + bp1);
}

__device__ __forceinline__ float epi_val(float v, float4 p, float shp, float bp1, int ORDER, bool SIG){
  v += p.w;  // bias
  if (ORDER == 0){ v = ssslu_f(v, shp, bp1); v = (v - p.z) * p.x + p.y; }
  else           { v = (v - p.z) * p.x + p.y; v = ssslu_f(v, shp, bp1); }
  if (SIG) v = 1.f / (1.f + __expf(-v));
  return v;
}

__device__ __forceinline__ void atomicMaxF(float* a, float v){
  if (v >= 0.f) atomicMax(reinterpret_cast<int*>(a), __float_as_int(v));
  else          atomicMin(reinterpret_cast<unsigned int*>(a), __float_as_uint(v));
}

__device__ __forceinline__ f16x8 mul8h(u16x8 a, u16x8 b){
  union{ u16x8 u; f16x8 h; } A, B; A.u = a; B.u = b;
  return A.h * B.h;
}

// =====================================================================
// x transpose: NCHW fp32 -> NHWC-256 f16 (XH). One (b,h) plane per block.
// =====================================================================
__global__ __launch_bounds__(256)
void xpose_k(const float* __restrict__ X, u16* __restrict__ XH)
{
  __shared__ u16 L[16384];   // 32 KB
  const int tid = threadIdx.x;
  const int b = blockIdx.x >> 6, h = blockIdx.x & 63;
  const float* xp = X + (size_t)b * 256 * 4096 + h * 64;
#pragma unroll
  for (int i = 0; i < 16; ++i){
    int ci = i * 16 + (tid >> 4);
    int w4 = (tid & 15) * 4;
    float4 v = *(const float4*)(xp + (size_t)ci * 4096 + w4);
    int sw = 4 * ((ci >> 3) & 15);
    u16x4 d;
    d[0] = f2h(v.x); d[1] = f2h(v.y); d[2] = f2h(v.z); d[3] = f2h(v.w);
    *(u16x4*)&L[ci * 64 + (w4 ^ sw)] = d;
  }
  __syncthreads();
  u16* out = XH + (((size_t)b * 4096 + (size_t)h * 64) << 8);
#pragma unroll
  for (int it = 0; it < 8; ++it){
    int w   = it * 8 + (tid >> 5);
    int m   = tid & 31;
    int ci0 = m * 8;
    int base = (w & ~3) ^ (4 * (m & 15));
    int wl   = w & 3;
    u16x8 o;
#pragma unroll
    for (int k = 0; k < 8; ++k)
      o[k] = L[(ci0 + k) * 64 + base + wl];
    *(u16x8*)&out[w * 256 + ci0] = o;
  }
}

// =====================================================================
// 3x3 conv, FAT-WAVE version: BM=128, BN=512 (8 h-rows), 256 thr / 4 waves,
// each wave computes TWO output rows (wave tile 128x128, acc0+acc1 = 256
// AGPR). Rationale: total waves = 1024 (1/SIMD) with 2x MFMA per
// barrier-period vs the old 128x64 tile -> more MFMA demand per SIMD.
// B window [2 buf][10 rows][66 wp][32 ci], PREFETCHED one chunk ahead
// (no per-chunk exposed stage, exactly one barrier per it).
// A double-buffered per it (3 taps). LDS 133632 B -> 1 block/CU.
// grid: (128, 2); y = co half.
// =====================================================================
template<int CI_T, bool CAT>
__global__ __launch_bounds__(256, 1)
void conv3_mfma(const u16* __restrict__ Apk, const u16* __restrict__ Bg,
                u16* __restrict__ DstH, const float4* __restrict__ pp,
                const u16* __restrict__ xahT_, const u16* __restrict__ xawT_,
                float shp, float bp1, int ORDER)
{
  constexpr int NCC = CI_T / 32;
  constexpr int NIT = NCC * 3;
  // sA: [2 buf][3 taps][128 m][32 ci] = 24576 u16 (49152 B) @ 0
  // sB: [2 buf][10 rows][66 wp][32 ci] = 42240 u16 (84480 B) @ 24576
  __shared__ __align__(16) u16 sAB[66816];   // 133632 B -> 1 block/CU

  const int tid  = threadIdx.x;
  const int lane = tid & 63;
  const int wv   = tid >> 6;        // 0..3; owns output rows 2wv, 2wv+1
  const int l15  = lane & 15, l4 = lane >> 4;

  const int bx  = blockIdx.x;                  // 0..127
  const int bid = (bx & 7) * 16 + (bx >> 3);   // bijective XCD swizzle (128 % 8 == 0)
  const int b   = bid >> 3;
  const int r0  = (bid & 7) * 8;               // output rows r0..r0+7
  const int m0  = blockIdx.y * 128;            // co half

  // ---- one-time zero of B pads in BOTH buffers ----
  for (int i = tid; i < 640; i += 256){
    int bu = i >> 5;              // 0..19 = buf*10 + row
    int rem = i & 31;
    int wp = (rem & 16) ? 65 : 0;
    *(u32*)&sAB[24576 + bu * 2112 + wp * 32 + (rem & 15) * 2] = 0;
  }
  if (r0 == 0)
    for (int i = tid; i < 1056; i += 256){
      *(u32*)&sAB[24576 + i * 2] = 0;
      *(u32*)&sAB[24576 + 21120 + i * 2] = 0;
    }
  if (r0 == 56)
    for (int i = tid; i < 1056; i += 256){
      *(u32*)&sAB[24576 + 9 * 2112 + i * 2] = 0;
      *(u32*)&sAB[24576 + 21120 + 9 * 2112 + i * 2] = 0;
    }

  // ---- fixed per-lane staging offsets (bytes) ----
  const int rA = tid >> 2, s4 = tid & 3;
  const u32 offA0 = ((u32)rA * CI_T + ((s4 ^ SWZ(rA)) << 3)) * 2;
  const u32 offA1 = ((u32)(rA + 64) * CI_T + ((s4 ^ SWZ(rA + 64)) << 3)) * 2;
  const u32 offB  = (((u32)rA << 8) + ((s4 ^ SWZ(rA + 1)) << 3)) * 2;   // rA doubles as w

  auto STAGE_A = [&](int it2){
    int d2 = it2 % 3, c2 = it2 / 3;
    u16* dst = &sAB[(it2 & 1) * 12288 + wv * 512];
    const char* pa = (const char*)(Apk + ((size_t)(d2 * 3 * 256) + m0) * CI_T + c2 * 32);
#pragma unroll
    for (int j2 = 0; j2 < 3; ++j2){
      gl16(pa + offA0, dst + j2 * 4096);
      gl16(pa + offA1, dst + j2 * 4096 + 2048);
      pa += (size_t)256 * CI_T * 2;
    }
  };
  auto STAGE_B = [&](int c2){
    const int bb = 24576 + (c2 & 1) * 21120;
#pragma unroll
    for (int j = 0; j < 10; ++j){
      int hh = r0 - 1 + j;
      if ((unsigned)hh >= 64u) continue;       // pad rows stay zero
      if (CAT && c2 < 8){
        int w = rA, s = s4;
        int ci0 = c2 * 32 + ((s ^ SWZ(w + 1)) << 3);
        u16x8 vh = *(const u16x8*)&xahT_[((b * 64 + hh) << 8) + ci0];
        u16x8 vw = *(const u16x8*)&xawT_[((b * 64 + w ) << 8) + ci0];
        *(f16x8*)&sAB[bb + j * 2112 + (w + 1) * 32 + s * 8] = mul8h(vh, vw);
      } else {
        int cio = CAT ? (c2 * 32 - 256) : (c2 * 32);
        const char* pb = (const char*)(Bg + (((size_t)b * 4096 + (size_t)hh * 64) << 8) + cio);
        gl16(pb + offB, &sAB[bb + j * 2112 + 32 + wv * 512]);
      }
    }
  };

  f32x4 acc0[8][4], acc1[8][4];
#pragma unroll
  for (int i = 0; i < 8; ++i)
#pragma unroll
    for (int j = 0; j < 4; ++j){
      acc0[i][j][0]=0.f; acc0[i][j][1]=0.f; acc0[i][j][2]=0.f; acc0[i][j][3]=0.f;
      acc1[i][j][0]=0.f; acc1[i][j][1]=0.f; acc1[i][j][2]=0.f; acc1[i][j][3]=0.f;
    }

  // ---- hoisted LDS read bases (bytes) ----
  const char* lds = (const char*)sAB;
  const u32 aoff = (u32)l15 * 64 + (u32)((l4 ^ ((l15 >> 1) & 3)) << 4);
  const char* ab0 = lds + aoff;
  const char* ab1 = lds + aoff + 24576;
  const u32 brow0 = 49152u + (u32)(2 * wv + 0) * 4224;
  const u32 brow1 = 49152u + (u32)(2 * wv + 1) * 4224;
#define BSW(dw) ((u32)(l15 + (dw)) * 64 + (u32)((l4 ^ (((l15 + (dw)) >> 1) & 3)) << 4))
  const char* ba0 = lds + brow0 + BSW(0);
  const char* ba1 = lds + brow0 + BSW(1);
  const char* ba2 = lds + brow0 + BSW(2);
  const char* bc0 = lds + brow1 + BSW(0);
  const char* bc1 = lds + brow1 + BSW(1);
  const char* bc2 = lds + brow1 + BSW(2);
#undef BSW

  STAGE_A(0);
  STAGE_B(0);
  __syncthreads();

  for (int c = 0; c < NCC; ++c){
    const u32 bofs = (c & 1) ? 42240u : 0u;
#pragma unroll
    for (int d = 0; d < 3; ++d){
      const int it = 3 * c + d;
      if (it + 1 < NIT) STAGE_A(it + 1);
      if (d == 0 && c + 1 < NCC) STAGE_B(c + 1);   // prefetch next chunk's B

      const char* ab = ((c + d) & 1) ? ab1 : ab0;
#pragma unroll
      for (int dw = 0; dw < 3; ++dw){
        const char* p0 = ((dw == 0) ? ba0 : (dw == 1) ? ba1 : ba2) + bofs + d * 4224;
        const char* p1 = ((dw == 0) ? bc0 : (dw == 1) ? bc1 : bc2) + bofs + d * 4224;
        f16x8 afr[8], b0r[4], b1r[4];
#pragma unroll
        for (int fm = 0; fm < 8; ++fm)
          afr[fm] = *(const f16x8*)(ab + dw * 8192 + fm * 1024);
#pragma unroll
        for (int fn = 0; fn < 4; ++fn){
          b0r[fn] = *(const f16x8*)(p0 + fn * 1024);
          b1r[fn] = *(const f16x8*)(p1 + fn * 1024);
        }
        __builtin_amdgcn_s_setprio(1);
#pragma unroll
        for (int fm = 0; fm < 8; ++fm)
#pragma unroll
          for (int fn = 0; fn < 4; ++fn){
            acc0[fm][fn] = __builtin_amdgcn_mfma_f32_16x16x32_f16(afr[fm], b0r[fn], acc0[fm][fn], 0, 0, 0);
            acc1[fm][fn] = __builtin_amdgcn_mfma_f32_16x16x32_f16(afr[fm], b1r[fn], acc1[fm][fn], 0, 0, 0);
          }
        __builtin_amdgcn_s_setprio(0);
      }
      __syncthreads();
    }
  }

  // ---------- epilogue: NHWC f16 store (2 rows) ----------
#pragma unroll
  for (int rr = 0; rr < 2; ++rr){
    const int h = r0 + 2 * wv + rr;
#pragma unroll
    for (int fm = 0; fm < 8; ++fm){
      const int cobase = m0 + fm * 16 + 4 * l4;
      float4 P0 = pp[cobase], P1 = pp[cobase+1], P2 = pp[cobase+2], P3 = pp[cobase+3];
#pragma unroll
      for (int fn = 0; fn < 4; ++fn){
        int w = fn * 16 + l15;
        f32x4 a = rr ? acc1[fm][fn] : acc0[fm][fn];
        float v0 = epi_val(a[0], P0, shp, bp1, ORDER, false);
        float v1 = epi_val(a[1], P1, shp, bp1, ORDER, false);
        float v2 = epi_val(a[2], P2, shp, bp1, ORDER, false);
        float v3 = epi_val(a[3], P3, shp, bp1, ORDER, false);
        uint2 st;
        st.x = (u32)f2h(v0) | ((u32)f2h(v1) << 16);
        st.y = (u32)f2h(v2) | ((u32)f2h(v3) << 16);
        *(uint2*)&DstH[(((size_t)b * 4096 + (size_t)h * 64 + w) << 8) + cobase] = st;
      }
    }
  }
}

// =====================================================================
// 1x1 conv, A-RESIDENT + barrier-free K-loop (unchanged from round 7).
// EPI: 1 = NHWC f16 store, 2 = NCHW fp32 + sigmoid (d_out).
// =====================================================================
template<int EPI>
__global__ __launch_bounds__(512, 2)
void conv1_res(const u16* __restrict__ Apk, const u16* __restrict__ Bg,
               u16* __restrict__ DstH, float* __restrict__ DstF,
               const float4* __restrict__ pp,
               float shp, float bp1, int ORDER)
{
  __shared__ __align__(16) u16 AL[65536];   // [8 c][256 m][32 ci] swizzled = 128 KB

  const int tid  = threadIdx.x;
  const int lane = tid & 63;
  const int wv   = tid >> 6;        // 0..7
  const int wm   = wv >> 2;         // 0..1 (M half: 128 co)
  const int wn   = wv & 3;          // 0..3 (h row)
  const int l15  = lane & 15, l4 = lane >> 4;

  const int bx   = blockIdx.x;
  const int bid  = (bx & 7) * 32 + (bx >> 3);  // bijective XCD swizzle (256 % 8 == 0)
  const int b    = bid >> 4;
  const int h0   = (bid & 15) * 4;

  {
    const int g0 = tid;
    const int g1 = 512 + tid;
    const int mA0 = g0 >> 2, sA0 = g0 & 3;
    const int mA1 = g1 >> 2, sA1 = g1 & 3;
    const u32 offA0 = ((u32)mA0 * 256 + ((sA0 ^ SWZ(mA0)) << 3)) * 2;
    const u32 offA1 = ((u32)mA1 * 256 + ((sA1 ^ SWZ(mA1)) << 3)) * 2;
#pragma unroll
    for (int c = 0; c < 8; ++c){
      const char* pa = (const char*)(Apk + c * 32);
      gl16(pa + offA0, &AL[c * 8192 + (wv * 64) * 8]);
      gl16(pa + offA1, &AL[c * 8192 + (512 + wv * 64) * 8]);
    }
  }

  const u16* Bp = Bg + (((size_t)b * 4096 + (size_t)(h0 + wn) * 64) << 8) + (l15 << 8) + (l4 << 3);
#define LDB(c, fn) (*(const f16x8*)(Bp + ((fn) * 16 << 8) + (c) * 32))

  f32x4 acc[8][4];
#pragma unroll
  for (int i = 0; i < 8; ++i)
#pragma unroll
    for (int j = 0; j < 4; ++j){ acc[i][j][0]=0.f; acc[i][j][1]=0.f; acc[i][j][2]=0.f; acc[i][j][3]=0.f; }

  f16x8 bn0 = LDB(0, 0), bn1 = LDB(0, 1), bn2 = LDB(0, 2), bn3 = LDB(0, 3);

  __syncthreads();   // the ONLY barrier: A resident from here on

  const char* abase = (const char*)AL + wm * 8192 + l15 * 64 + ((l4 ^ SWZ(l15)) << 4);

#pragma unroll
  for (int c = 0; c < 8; ++c){
    f16x8 b0 = bn0, b1 = bn1, b2 = bn2, b3 = bn3;
    if (c < 7){
      bn0 = LDB(c + 1, 0); bn1 = LDB(c + 1, 1); bn2 = LDB(c + 1, 2); bn3 = LDB(c + 1, 3);
    }
    f16x8 afr[8];
#pragma unroll
    for (int fm = 0; fm < 8; ++fm)
      afr[fm] = *(const f16x8*)(abase + c * 16384 + fm * 1024);
    __builtin_amdgcn_s_setprio(1);
#pragma unroll
    for (int fm = 0; fm < 8; ++fm){
      acc[fm][0] = __builtin_amdgcn_mfma_f32_16x16x32_f16(afr[fm], b0, acc[fm][0], 0, 0, 0);
      acc[fm][1] = __builtin_amdgcn_mfma_f32_16x16x32_f16(afr[fm], b1, acc[fm][1], 0, 0, 0);
      acc[fm][2] = __builtin_amdgcn_mfma_f32_16x16x32_f16(afr[fm], b2, acc[fm][2], 0, 0, 0);
      acc[fm][3] = __builtin_amdgcn_mfma_f32_16x16x32_f16(afr[fm], b3, acc[fm][3], 0, 0, 0);
    }
    __builtin_amdgcn_s_setprio(0);
  }
#undef LDB

  const int h = h0 + wn;
#pragma unroll
  for (int fm = 0; fm < 8; ++fm){
    const int cobase = wm * 128 + fm * 16 + 4 * l4;
    float4 P0 = pp[cobase], P1 = pp[cobase+1], P2 = pp[cobase+2], P3 = pp[cobase+3];
#pragma unroll
    for (int fn = 0; fn < 4; ++fn){
      int w = fn * 16 + l15;
      if (EPI == 1){
        float v0 = epi_val(acc[fm][fn][0], P0, shp, bp1, ORDER, false);
        float v1 = epi_val(acc[fm][fn][1], P1, shp, bp1, ORDER, false);
        float v2 = epi_val(acc[fm][fn][2], P2, shp, bp1, ORDER, false);
        float v3 = epi_val(acc[fm][fn][3], P3, shp, bp1, ORDER, false);
        uint2 st;
        st.x = (u32)f2h(v0) | ((u32)f2h(v1) << 16);
        st.y = (u32)f2h(v2) | ((u32)f2h(v3) << 16);
        *(uint2*)&DstH[(((size_t)b * 4096 + (size_t)h * 64 + w) << 8) + cobase] = st;
      } else {
        float v0 = epi_val(acc[fm][fn][0], P0, shp, bp1, ORDER, true);
        float v1 = epi_val(acc[fm][fn][1], P1, shp, bp1, ORDER, true);
        float v2 = epi_val(acc[fm][fn][2], P2, shp, bp1, ORDER, true);
        float v3 = epi_val(acc[fm][fn][3], P3, shp, bp1, ORDER, true);
        size_t base = ((size_t)(b * 256 + cobase)) * 4096 + (size_t)h * 64 + w;
        DstF[base]          = v0;
        DstF[base + 4096]   = v1;
        DstF[base + 2*4096] = v2;
        DstF[base + 3*4096] = v3;
      }
    }
  }
}

// =====================================================================
// Fused pool: ONE read of activated NHWC tensor T -> rowp (full) + colp
// (atomicMaxF partials). Block = (b, h-quartet); grid 256.
// =====================================================================
__global__ __launch_bounds__(256)
void pool2_k(const u16* __restrict__ T, float* __restrict__ rowp, float* __restrict__ colp)
{
  __shared__ float L[8][256];
  const int tid = threadIdx.x;
  const int b = blockIdx.x >> 4, hq = blockIdx.x & 15;
  const int wg = tid >> 5;             // 0..7 (8-w group)
  const int c8 = (tid & 31) * 8;
  float cp[8][8];                      // [j: w-in-group][e: c]
#pragma unroll
  for (int j = 0; j < 8; ++j)
#pragma unroll
    for (int e = 0; e < 8; ++e) cp[j][e] = -3.0e38f;

#pragma unroll
  for (int hi = 0; hi < 4; ++hi){
    const int h = hq * 4 + hi;
    const u16* base = T + (((size_t)b * 4096 + (size_t)h * 64) << 8) + c8;
    float m[8];
#pragma unroll
    for (int e = 0; e < 8; ++e) m[e] = -3.0e38f;
#pragma unroll
    for (int j = 0; j < 8; ++j){
      u16x8 v = *(const u16x8*)(base + ((wg * 8 + j) << 8));
#pragma unroll
      for (int e = 0; e < 8; ++e){
        float f = h2f(v[e]);
        m[e] = fmaxf(m[e], f);
        cp[j][e] = fmaxf(cp[j][e], f);
      }
    }
#pragma unroll
    for (int e = 0; e < 8; ++e) L[wg][c8 + e] = m[e];
    __syncthreads();
    float r = L[0][tid];
#pragma unroll
    for (int g = 1; g < 8; ++g) r = fmaxf(r, L[g][tid]);
    rowp[(((b << 8) | tid) << 6) + h] = r;
    __syncthreads();
  }
#pragma unroll
  for (int e = 0; e < 8; ++e)
#pragma unroll
    for (int j = 0; j < 8; ++j)
      atomicMaxF(&colp[(((b << 8) | (c8 + e)) << 6) + wg * 8 + j], cp[j][e]);
}

__global__ void initpool_k(float* __restrict__ p)
{
  int i = blockIdx.x * 1024 + threadIdx.x * 4;
  float4 v = make_float4(-3.0e38f, -3.0e38f, -3.0e38f, -3.0e38f);
  *(float4*)(p + i) = v;
}

// ---------------- attention + LN/SiLU; writes transposed fp16 ----------------
__device__ __forceinline__ float ln_silu_wave(float v){
  float mu = wred_sum(v) * (1.f / 64.f);
  float d = v - mu;
  float var = wred_sum(d * d) * (1.f / 64.f);
  float hn = d * rsqrtf(var + 1e-5f);
  return hn / (1.f + __expf(-hn));
}

__global__ void attn_k(const float* __restrict__ qw, const float* __restrict__ kw,
                       const float* __restrict__ qh, const float* __restrict__ kh,
                       u16* __restrict__ xahT, u16* __restrict__ xawT)
{
  int row  = blockIdx.x * 4 + (threadIdx.x >> 6);
  int lane = threadIdx.x & 63;
  int idx  = (row << 6) + lane;
  float qwv = qw[idx], kwv = kw[idx], qhv = qh[idx], khv = kh[idx];
  float Pq = wred_max(qwv), mq = wred_min(qwv);
  float Pk = wred_max(khv), mk = wred_min(khv);
  float aw = fmaxf(kwv * Pq, kwv * mq);
  float ah = fmaxf(qhv * Pk, qhv * mk);
  aw = ln_silu_wave(aw);
  ah = ln_silu_wave(ah);
  int b = row >> 8, q = row & 255;
  xawT[((b * 64 + lane) << 8) + q] = f2h(aw);
  xahT[((b * 64 + lane) << 8) + q] = f2h(ah);
}

// ---------------- weight/param pack (fp16) ----------------
__global__ void pack_k(const float* __restrict__ wqkv, const float* __restrict__ wco,
                       const float* __restrict__ wb1, const float* __restrict__ wb2,
                       const float* gq, const float* bq, const float* mq, const float* vq,
                       const float* gc, const float* bc, const float* mc, const float* vc,
                       const float* g1, const float* b1, const float* m1, const float* v1, const float* bias1,
                       const float* g2, const float* b2, const float* m2, const float* v2, const float* bias2,
                       u16* __restrict__ WQ, u16* __restrict__ WCO, u16* __restrict__ WB1, u16* __restrict__ WB2,
                       float4* __restrict__ PP)
{
  const int E0 = 196608, E1 = 196608 + 1179648, E2 = 196608 + 1179648 + 589824, E3 = 2031616;
  int i = blockIdx.x * 256 + threadIdx.x;
  if (i >= E3 + 1536) return;
  if (i < E0){ WQ[i] = f2h(wqkv[i]); }
  else if (i < E1){
    int d = i - E0; int tap = d / 131072; int rm = d % 131072; int m = rm >> 9; int ci = rm & 511;
    WCO[d] = f2h(wco[(size_t)((m << 9) | ci) * 9 + tap]);
  } else if (i < E2){
    int d = i - E1; int tap = d / 65536; int rm = d & 65535; int m = rm >> 8; int ci = rm & 255;
    WB1[d] = f2h(wb1[(size_t)((m << 8) | ci) * 9 + tap]);
  } else if (i < E3){
    int d = i - E2; WB2[d] = f2h(wb2[d]);
  } else {
    int c = i - E3;
    float g, be, mm, vv, bi;
    if (c < 768){ g = gq[c]; be = bq[c]; mm = mq[c]; vv = vq[c]; bi = 0.f; }
    else if (c < 1024){ int j = c - 768;  g = gc[j]; be = bc[j]; mm = mc[j]; vv = vc[j]; bi = 0.f; }
    else if (c < 1280){ int j = c - 1024; g = g1[j]; be = b1[j]; mm = m1[j]; vv = v1[j]; bi = bias1[j]; }
    else              { int j = c - 1280; g = g2[j]; be = b2[j]; mm = m2[j]; vv = v2[j]; bi = bias2[j]; }
    PP[c] = make_float4(g / sqrtf(vv + 1e-3f), be, mm, bi);
  }
}

// ---------------- launch ----------------
extern "C" void kernel_launch(void* const* d_in, const int* in_sizes, int n_in,
                              void* d_out, int out_size, void* d_ws, size_t ws_size,
                              hipStream_t stream)
{
  const float* x       = (const float*)d_in[0];
  const float* w_qkv   = (const float*)d_in[1];
  const float* g_qkv   = (const float*)d_in[2];
  const float* b_qkv   = (const float*)d_in[3];
  const float* m_qkv   = (const float*)d_in[4];
  const float* v_qkv   = (const float*)d_in[5];
  const float* w_co    = (const float*)d_in[6];
  const float* g_co    = (const float*)d_in[7];
  const float* b_co    = (const float*)d_in[8];
  const float* m_co    = (const float*)d_in[9];
  const float* v_co    = (const float*)d_in[10];
  const float* w_b1    = (const float*)d_in[11];
  const float* bias_b1 = (const float*)d_in[12];
  const float* g_b1    = (const float*)d_in[13];
  const float* b_b1    = (const float*)d_in[14];
  const float* m_b1    = (const float*)d_in[15];
  const float* v_b1    = (const float*)d_in[16];
  const float* w_b2    = (const float*)d_in[17];
  const float* bias_b2 = (const float*)d_in[18];
  const float* g_b2    = (const float*)d_in[19];
  const float* b_b2    = (const float*)d_in[20];
  const float* m_b2    = (const float*)d_in[21];
  const float* v_b2    = (const float*)d_in[22];
  float* out = (float*)d_out;

  // ---- workspace layout (bytes) ----
  char* W = (char*)d_ws;
  u16*    WQ   = (u16*)(W + 0);              // 768*256            -> 393216
  u16*    WCO  = (u16*)(W + 393216);         // 9*256*512          -> 2359296
  u16*    WB1  = (u16*)(W + 2752512);        // 9*256*256          -> 1179648
  u16*    WB2  = (u16*)(W + 3932160);        // 256*256            -> 131072
  float4* PP   = (float4*)(W + 4063232);     // 1536*16            -> 24576
  // Time-shared 33.5 MB slot: TQ (q acts) -> TK (k acts) -> TV (v acts) -> Y2
  u16*    TQK  = (u16*)(W + 4087808);        // 16*4096*256 f16    -> ends 37642240
  u16*    TV   = TQK;
  u16*    XAHT = (u16*)(W + 37642240);       // 16*64*256 f16      -> 524288
  u16*    XAWT = (u16*)(W + 38166528);       //                    -> 524288
  u16*    XH   = (u16*)(W + 38690816);       // x NHWC f16, 33.5MB (dead after conv-v)
  u16*    Y1   = (u16*)(W + 38690816);       // overlays XH (written by G2, after XH dead)
  u16*    Y2   = TV;                          // TV dead after G2
  float*  qh_  = (float*)(W + 72245248);     // 1 MB
  float*  kh_  = (float*)(W + 73293824);     // 1 MB
  float*  qw_  = (float*)(W + 74342400);     // 1 MB
  float*  kw_  = (float*)(W + 75390976);     // 1 MB

  const size_t NEED = 76439552;
  if (ws_size < NEED) return;

  const float SHP_N3 = -3.0f * PI_F * 0.5f;
  const float SHP_1  =  1.0f * PI_F * 0.5f;
  const float SHP_08 =  0.8f * PI_F * 0.5f;

  dim3 blk(256);

  pack_k<<<7942, blk, 0, stream>>>(w_qkv, w_co, w_b1, w_b2,
      g_qkv, b_qkv, m_qkv, v_qkv,
      g_co,  b_co,  m_co,  v_co,
      g_b1,  b_b1,  m_b1,  v_b1,  bias_b1,
      g_b2,  b_b2,  m_b2,  v_b2,  bias_b2,
      WQ, WCO, WB1, WB2, PP);

  // G0: transpose x -> NHWC-256 f16
  xpose_k<<<1024, blk, 0, stream>>>(x, XH);

  // init col pools (qw_ + kw_, contiguous 2 MB)
  initpool_k<<<512, blk, 0, stream>>>(qw_);

  // G1-q: qkv conv channels 0..255 (q) -> TQK; fused-read pools
  conv1_res<1><<<256, 512, 0, stream>>>(
      WQ, XH, TQK, nullptr, PP, SHP_N3, 1.3f, 0);
  pool2_k<<<256, blk, 0, stream>>>(TQK, qh_, qw_);

  // G1-k: channels 256..511 (k) -> TQK (TQ dead); pools
  conv1_res<1><<<256, 512, 0, stream>>>(
      WQ + (size_t)256 * 256, XH, TQK, nullptr, PP + 256, SHP_N3, 1.3f, 0);
  pool2_k<<<256, blk, 0, stream>>>(TQK, kh_, kw_);

  // attention
  attn_k<<<1024, blk, 0, stream>>>(qw_, kw_, qh_, kh_, XAHT, XAWT);

  // G1-v: channels 512..767 (v) -> TV (TK dead)
  conv1_res<1><<<256, 512, 0, stream>>>(
      WQ + (size_t)512 * 256, XH, TV, nullptr, PP + 512, SHP_N3, 1.3f, 0);

  // G2: co 3x3 conv over implicit concat [xa | xv] -> bn -> ssslu(1,0) -> Y1
  conv3_mfma<512, true><<<dim3(128, 2), blk, 0, stream>>>(
      WCO, TV, Y1, PP + 768, XAHT, XAWT, SHP_1, 1.0f, 1);

  // G3: b1 3x3 conv (+bias) -> ssslu(-3,0.3) -> bn -> Y2
  conv3_mfma<256, false><<<dim3(128, 2), blk, 0, stream>>>(
      WB1, Y1, Y2, PP + 1024, nullptr, nullptr, SHP_N3, 1.3f, 0);

  // G4: b2 1x1 conv (+bias) -> bn -> ssslu(0.8,0) -> sigmoid -> out
  conv1_res<2><<<256, 512, 0, stream>>>(
      WB2, Y2, nullptr, out, PP + 1280, SHP_08, 1.0f, 1);
}

// Round 9
// 391.901 us; speedup vs baseline: 1.5520x; 1.5520x over previous
//
#include <hip/hip_runtime.h>
#include <hip/hip_bf16.h>
#include <math.h>

#define PI_F 3.14159265358979323846f

typedef unsigned short u16;
typedef unsigned int   u32;
typedef float    f32x4 __attribute__((ext_vector_type(4)));
typedef _Float16 f16x8 __attribute__((ext_vector_type(8)));
typedef u16      u16x8 __attribute__((ext_vector_type(8)));
typedef u16      u16x4 __attribute__((ext_vector_type(4)));

__device__ __forceinline__ u16 f2h(float f){ union{ _Float16 h; u16 u; } c; c.h = (_Float16)f; return c.u; }
__device__ __forceinline__ float h2f(u16 u){ union{ u16 u; _Float16 h; } c; c.u = u; return (float)c.h; }

__device__ __forceinline__ void gl16(const void* g, void* l){
  __builtin_amdgcn_global_load_lds((const __attribute__((address_space(1))) u32*)g,
                                   (__attribute__((address_space(3))) u32*)l, 16, 0, 0);
}

__device__ __forceinline__ int SWZ(int r){ return (r>>1)&3; }

__device__ __forceinline__ float wred_max(float v){
#pragma unroll
  for (int m = 32; m; m >>= 1) v = fmaxf(v, __shfl_xor(v, m));
  return v;
}
__device__ __forceinline__ float wred_min(float v){
#pragma unroll
  for (int m = 32; m; m >>= 1) v = fminf(v, __shfl_xor(v, m));
  return v;
}
__device__ __forceinline__ float wred_sum(float v){
#pragma unroll
  for (int m = 32; m; m >>= 1) v += __shfl_xor(v, m);
  return v;
}

__device__ __forceinline__ float ssslu_f(float x, float shp, float bp1){
  float s = x / (1.0f + fabsf(x));
  return x * (__sinf(s * shp) + bp1);
}

__device__ __forceinline__ float epi_val(float v, float4 p, float shp, float bp1, int ORDER, bool SIG){
  v += p.w;  // bias
  if (ORDER == 0){ v = ssslu_f(v, shp, bp1); v = (v - p.z) * p.x + p.y; }
  else           { v = (v - p.z) * p.x + p.y; v = ssslu_f(v, shp, bp1); }
  if (SIG) v = 1.f / (1.f + __expf(-v));
  return v;
}

__device__ __forceinline__ f16x8 mul8h(u16x8 a, u16x8 b){
  union{ u16x8 u; f16x8 h; } A, B; A.u = a; B.u = b;
  return A.h * B.h;
}

// =====================================================================
// x transpose: NCHW fp32 -> NHWC-256 f16 (XH). One (b,h) plane per block.
// =====================================================================
__global__ __launch_bounds__(256)
void xpose_k(const float* __restrict__ X, u16* __restrict__ XH)
{
  __shared__ u16 L[16384];   // 32 KB
  const int tid = threadIdx.x;
  const int b = blockIdx.x >> 6, h = blockIdx.x & 63;
  const float* xp = X + (size_t)b * 256 * 4096 + h * 64;
#pragma unroll
  for (int i = 0; i < 16; ++i){
    int ci = i * 16 + (tid >> 4);
    int w4 = (tid & 15) * 4;
    float4 v = *(const float4*)(xp + (size_t)ci * 4096 + w4);
    int sw = 4 * ((ci >> 3) & 15);
    u16x4 d;
    d[0] = f2h(v.x); d[1] = f2h(v.y); d[2] = f2h(v.z); d[3] = f2h(v.w);
    *(u16x4*)&L[ci * 64 + (w4 ^ sw)] = d;
  }
  __syncthreads();
  u16* out = XH + (((size_t)b * 4096 + (size_t)h * 64) << 8);
#pragma unroll
  for (int it = 0; it < 8; ++it){
    int w   = it * 8 + (tid >> 5);
    int m   = tid & 31;
    int ci0 = m * 8;
    int base = (w & ~3) ^ (4 * (m & 15));
    int wl   = w & 3;
    u16x8 o;
#pragma unroll
    for (int k = 0; k < 8; ++k)
      o[k] = L[(ci0 + k) * 64 + base + wl];
    *(u16x8*)&out[w * 256 + ci0] = o;
  }
}

// =====================================================================
// 3x3 conv, BM=128, BN=256 (4 h x 64 w), 256 thr / 4 waves, 2 blocks/CU.
// (round-7 geometry, VALU-lean loop)
// NEW: B is REG-STAGED (T14): global->reg a full chunk early, ds_write at
// d==0. The d==0 barrier no longer drains a just-issued global load.
// =====================================================================
template<int CI_T, bool CAT>
__global__ __launch_bounds__(256, 2)
void conv3_mfma(const u16* __restrict__ Apk, const u16* __restrict__ Bg,
                u16* __restrict__ DstH, const float4* __restrict__ pp,
                const u16* __restrict__ xahT_, const u16* __restrict__ xawT_,
                float shp, float bp1, int ORDER)
{
  constexpr int NCC = CI_T / 32;
  constexpr int NIT = NCC * 3;
  // sA: [2 buf][3 taps][128 m][32 ci] = 24576 u16 (49152 B) @ 0
  // sB: [6 rows][66 wp][32 ci]        = 12672 u16 (25344 B) @ 24576
  __shared__ __align__(16) u16 sAB[37248];   // 74496 B -> 2 blocks/CU

  const int tid  = threadIdx.x;
  const int lane = tid & 63;
  const int wv   = tid >> 6;        // 0..3
  const int wn   = wv;              // h row within quad
  const int l15  = lane & 15, l4 = lane >> 4;

  const int bx  = blockIdx.x;
  const int bid = (bx & 7) * 32 + (bx >> 3);   // bijective XCD swizzle (256 % 8 == 0)
  const int b   = bid >> 4;
  const int r0  = (bid & 15) * 4;              // output rows r0..r0+3
  const int m0  = blockIdx.y * 128;            // co half

  // ---- one-time zero of B pads (never overwritten by staging) ----
  if (tid < 192){
    int rr = tid >> 5, rem = tid & 31;
    int wp = (rem & 16) ? 65 : 0;
    *(u32*)&sAB[24576 + rr * 2112 + wp * 32 + (rem & 15) * 2] = 0;
  }
  if (r0 == 0)
    for (int i = tid; i < 1056; i += 256) *(u32*)&sAB[24576 + i * 2] = 0;
  if (r0 == 60)
    for (int i = tid; i < 1056; i += 256) *(u32*)&sAB[24576 + 5 * 2112 + i * 2] = 0;

  // ---- fixed per-lane staging offsets (bytes) ----
  const int rA = tid >> 2, s4 = tid & 3;
  const u32 offA0 = ((u32)rA * CI_T + ((s4 ^ SWZ(rA)) << 3)) * 2;
  const u32 offA1 = ((u32)(rA + 64) * CI_T + ((s4 ^ SWZ(rA + 64)) << 3)) * 2;
  const u32 offB  = (((u32)rA << 8) + ((s4 ^ SWZ(rA + 1)) << 3)) * 2;   // rA doubles as w

  auto STAGE_A = [&](int it2){
    int d2 = it2 % 3, c2 = it2 / 3;
    u16* dst = &sAB[(it2 & 1) * 12288 + wv * 512];
    const char* pa = (const char*)(Apk + ((size_t)(d2 * 3 * 256) + m0) * CI_T + c2 * 32);
#pragma unroll
    for (int j2 = 0; j2 < 3; ++j2){
      gl16(pa + offA0, dst + j2 * 4096);
      gl16(pa + offA1, dst + j2 * 4096 + 2048);
      pa += (size_t)256 * CI_T * 2;
    }
  };

  // ---- reg-staged B ----
  u16x8 br[6];
  auto LOADB = [&](int c2){
    if (CAT && c2 < 8) return;                 // compute path, nothing to preload
    int cio = CAT ? (c2 * 32 - 256) : (c2 * 32);
#pragma unroll
    for (int j = 0; j < 6; ++j){
      int hh = r0 - 1 + j;
      if ((unsigned)hh >= 64u) continue;       // pad rows stay zero
      const char* pb = (const char*)(Bg + (((size_t)b * 4096 + (size_t)hh * 64) << 8) + cio);
      br[j] = *(const u16x8*)(pb + offB);
    }
  };
  auto WRITEB = [&](int c2){
    if (CAT && c2 < 8){
#pragma unroll
      for (int j = 0; j < 6; ++j){
        int hh = r0 - 1 + j;
        if ((unsigned)hh >= 64u) continue;
        int ci0 = c2 * 32 + ((s4 ^ SWZ(rA + 1)) << 3);
        u16x8 vh = *(const u16x8*)&xahT_[((b * 64 + hh) << 8) + ci0];
        u16x8 vw = *(const u16x8*)&xawT_[((b * 64 + rA) << 8) + ci0];
        *(f16x8*)&sAB[24576 + j * 2112 + 32 + 8 * tid] = mul8h(vh, vw);
      }
    } else {
#pragma unroll
      for (int j = 0; j < 6; ++j){
        int hh = r0 - 1 + j;
        if ((unsigned)hh >= 64u) continue;
        *(u16x8*)&sAB[24576 + j * 2112 + 32 + 8 * tid] = br[j];
      }
    }
  };

  f32x4 acc[8][4];
#pragma unroll
  for (int i = 0; i < 8; ++i)
#pragma unroll
    for (int j = 0; j < 4; ++j){ acc[i][j][0]=0.f; acc[i][j][1]=0.f; acc[i][j][2]=0.f; acc[i][j][3]=0.f; }

  // ---- hoisted LDS read bases (bytes) ----
  const char* lds = (const char*)sAB;
  const u32 aoff = (u32)l15 * 64 + (u32)((l4 ^ ((l15 >> 1) & 3)) << 4);
  const char* ab0 = lds + aoff;
  const char* ab1 = lds + aoff + 24576;
  const u32 bcom = 49152u + (u32)wn * 4224;
  const char* bb0 = lds + bcom + (u32)(l15 + 0) * 64 + (u32)((l4 ^ (((l15 + 0) >> 1) & 3)) << 4);
  const char* bb1 = lds + bcom + (u32)(l15 + 1) * 64 + (u32)((l4 ^ (((l15 + 1) >> 1) & 3)) << 4);
  const char* bb2 = lds + bcom + (u32)(l15 + 2) * 64 + (u32)((l4 ^ (((l15 + 2) >> 1) & 3)) << 4);

  STAGE_A(0);
  LOADB(0);

  for (int c = 0; c < NCC; ++c){
#pragma unroll
    for (int d = 0; d < 3; ++d){
      const int it = 3 * c + d;
      if (it + 1 < NIT) STAGE_A(it + 1);
      if (d == 0){
        WRITEB(c);                     // regs loaded a full chunk ago
        if (c + 1 < NCC) LOADB(c + 1); // issue next chunk's B early
        __syncthreads();
      }

      const char* ab = ((c + d) & 1) ? ab1 : ab0;
#pragma unroll
      for (int dw = 0; dw < 3; ++dw){
        const char* bp = (dw == 0) ? bb0 : (dw == 1) ? bb1 : bb2;
        f16x8 afr[8], bfr[4];
#pragma unroll
        for (int fm = 0; fm < 8; ++fm)
          afr[fm] = *(const f16x8*)(ab + dw * 8192 + fm * 1024);
#pragma unroll
        for (int fn = 0; fn < 4; ++fn)
          bfr[fn] = *(const f16x8*)(bp + d * 4224 + fn * 1024);
        __builtin_amdgcn_s_setprio(1);
#pragma unroll
        for (int fm = 0; fm < 8; ++fm)
#pragma unroll
          for (int fn = 0; fn < 4; ++fn)
            acc[fm][fn] = __builtin_amdgcn_mfma_f32_16x16x32_f16(afr[fm], bfr[fn], acc[fm][fn], 0, 0, 0);
        __builtin_amdgcn_s_setprio(0);
      }
      __syncthreads();
    }
  }

  // ---------- epilogue: NHWC f16 store ----------
  const int h = r0 + wn;
#pragma unroll
  for (int fm = 0; fm < 8; ++fm){
    const int cobase = m0 + fm * 16 + 4 * l4;
    float4 P0 = pp[cobase], P1 = pp[cobase+1], P2 = pp[cobase+2], P3 = pp[cobase+3];
#pragma unroll
    for (int fn = 0; fn < 4; ++fn){
      int w = fn * 16 + l15;
      float v0 = epi_val(acc[fm][fn][0], P0, shp, bp1, ORDER, false);
      float v1 = epi_val(acc[fm][fn][1], P1, shp, bp1, ORDER, false);
      float v2 = epi_val(acc[fm][fn][2], P2, shp, bp1, ORDER, false);
      float v3 = epi_val(acc[fm][fn][3], P3, shp, bp1, ORDER, false);
      uint2 st;
      st.x = (u32)f2h(v0) | ((u32)f2h(v1) << 16);
      st.y = (u32)f2h(v2) | ((u32)f2h(v3) << 16);
      *(uint2*)&DstH[(((size_t)b * 4096 + (size_t)h * 64 + w) << 8) + cobase] = st;
    }
  }
}

// =====================================================================
// 1x1 conv, A-RESIDENT + barrier-free K-loop.
// NEW: depth-2 B prefetch (bq[2][4], all indices compile-time).
// EPI: 1 = NHWC f16 store, 2 = NCHW fp32 + sigmoid (d_out).
// =====================================================================
template<int EPI>
__global__ __launch_bounds__(512, 2)
void conv1_res(const u16* __restrict__ Apk, const u16* __restrict__ Bg,
               u16* __restrict__ DstH, float* __restrict__ DstF,
               const float4* __restrict__ pp,
               float shp, float bp1, int ORDER)
{
  __shared__ __align__(16) u16 AL[65536];   // [8 c][256 m][32 ci] swizzled = 128 KB

  const int tid  = threadIdx.x;
  const int lane = tid & 63;
  const int wv   = tid >> 6;        // 0..7
  const int wm   = wv >> 2;         // 0..1 (M half: 128 co)
  const int wn   = wv & 3;          // 0..3 (h row)
  const int l15  = lane & 15, l4 = lane >> 4;

  const int bx   = blockIdx.x;
  const int bid  = (bx & 7) * 32 + (bx >> 3);  // bijective XCD swizzle (256 % 8 == 0)
  const int b    = bid >> 4;
  const int h0   = (bid & 15) * 4;

  {
    const int g0 = tid;
    const int g1 = 512 + tid;
    const int mA0 = g0 >> 2, sA0 = g0 & 3;
    const int mA1 = g1 >> 2, sA1 = g1 & 3;
    const u32 offA0 = ((u32)mA0 * 256 + ((sA0 ^ SWZ(mA0)) << 3)) * 2;
    const u32 offA1 = ((u32)mA1 * 256 + ((sA1 ^ SWZ(mA1)) << 3)) * 2;
#pragma unroll
    for (int c = 0; c < 8; ++c){
      const char* pa = (const char*)(Apk + c * 32);
      gl16(pa + offA0, &AL[c * 8192 + (wv * 64) * 8]);
      gl16(pa + offA1, &AL[c * 8192 + (512 + wv * 64) * 8]);
    }
  }

  const u16* Bp = Bg + (((size_t)b * 4096 + (size_t)(h0 + wn) * 64) << 8) + (l15 << 8) + (l4 << 3);
#define LDB(c, fn) (*(const f16x8*)(Bp + ((fn) * 16 << 8) + (c) * 32))

  f32x4 acc[8][4];
#pragma unroll
  for (int i = 0; i < 8; ++i)
#pragma unroll
    for (int j = 0; j < 4; ++j){ acc[i][j][0]=0.f; acc[i][j][1]=0.f; acc[i][j][2]=0.f; acc[i][j][3]=0.f; }

  f16x8 bq[2][4];
#pragma unroll
  for (int fn = 0; fn < 4; ++fn) bq[0][fn] = LDB(0, fn);
#pragma unroll
  for (int fn = 0; fn < 4; ++fn) bq[1][fn] = LDB(1, fn);

  __syncthreads();   // the ONLY barrier: A resident from here on

  const char* abase = (const char*)AL + wm * 8192 + l15 * 64 + ((l4 ^ SWZ(l15)) << 4);

#pragma unroll
  for (int c = 0; c < 8; ++c){
    f16x8 afr[8];
#pragma unroll
    for (int fm = 0; fm < 8; ++fm)
      afr[fm] = *(const f16x8*)(abase + c * 16384 + fm * 1024);
    __builtin_amdgcn_s_setprio(1);
#pragma unroll
    for (int fm = 0; fm < 8; ++fm){
      acc[fm][0] = __builtin_amdgcn_mfma_f32_16x16x32_f16(afr[fm], bq[c & 1][0], acc[fm][0], 0, 0, 0);
      acc[fm][1] = __builtin_amdgcn_mfma_f32_16x16x32_f16(afr[fm], bq[c & 1][1], acc[fm][1], 0, 0, 0);
      acc[fm][2] = __builtin_amdgcn_mfma_f32_16x16x32_f16(afr[fm], bq[c & 1][2], acc[fm][2], 0, 0, 0);
      acc[fm][3] = __builtin_amdgcn_mfma_f32_16x16x32_f16(afr[fm], bq[c & 1][3], acc[fm][3], 0, 0, 0);
    }
    __builtin_amdgcn_s_setprio(0);
    if (c + 2 < 8){
#pragma unroll
      for (int fn = 0; fn < 4; ++fn) bq[c & 1][fn] = LDB(c + 2, fn);
    }
  }
#undef LDB

  const int h = h0 + wn;
#pragma unroll
  for (int fm = 0; fm < 8; ++fm){
    const int cobase = wm * 128 + fm * 16 + 4 * l4;
    float4 P0 = pp[cobase], P1 = pp[cobase+1], P2 = pp[cobase+2], P3 = pp[cobase+3];
#pragma unroll
    for (int fn = 0; fn < 4; ++fn){
      int w = fn * 16 + l15;
      if (EPI == 1){
        float v0 = epi_val(acc[fm][fn][0], P0, shp, bp1, ORDER, false);
        float v1 = epi_val(acc[fm][fn][1], P1, shp, bp1, ORDER, false);
        float v2 = epi_val(acc[fm][fn][2], P2, shp, bp1, ORDER, false);
        float v3 = epi_val(acc[fm][fn][3], P3, shp, bp1, ORDER, false);
        uint2 st;
        st.x = (u32)f2h(v0) | ((u32)f2h(v1) << 16);
        st.y = (u32)f2h(v2) | ((u32)f2h(v3) << 16);
        *(uint2*)&DstH[(((size_t)b * 4096 + (size_t)h * 64 + w) << 8) + cobase] = st;
      } else {
        float v0 = epi_val(acc[fm][fn][0], P0, shp, bp1, ORDER, true);
        float v1 = epi_val(acc[fm][fn][1], P1, shp, bp1, ORDER, true);
        float v2 = epi_val(acc[fm][fn][2], P2, shp, bp1, ORDER, true);
        float v3 = epi_val(acc[fm][fn][3], P3, shp, bp1, ORDER, true);
        size_t base = ((size_t)(b * 256 + cobase)) * 4096 + (size_t)h * 64 + w;
        DstF[base]          = v0;
        DstF[base + 4096]   = v1;
        DstF[base + 2*4096] = v2;
        DstF[base + 3*4096] = v3;
      }
    }
  }
}

// =====================================================================
// Pool kernels over an activated NHWC-256 f16 tensor T [b][h][w][256c].
// poolh: rowp[b,c,h] = max_w T   — one (b,h) plane per block (32 KB coalesced)
// poolw: colp[b,c,w] = max_h T   — one (b,w) column per block
// =====================================================================
__global__ __launch_bounds__(256)
void poolh_k(const u16* __restrict__ T, float* __restrict__ rowp)
{
  __shared__ float L[8][256];
  const int tid = threadIdx.x;
  const int b = blockIdx.x >> 6, h = blockIdx.x & 63;
  const int wg = tid >> 5;             // 0..7 (8-w group)
  const int c8 = (tid & 31) * 8;
  const u16* base = T + (((size_t)b * 4096 + (size_t)h * 64) << 8) + c8;
  float m[8];
#pragma unroll
  for (int e = 0; e < 8; ++e) m[e] = -3.0e38f;
#pragma unroll
  for (int j = 0; j < 8; ++j){
    u16x8 v = *(const u16x8*)(base + ((wg * 8 + j) << 8));
#pragma unroll
    for (int e = 0; e < 8; ++e) m[e] = fmaxf(m[e], h2f(v[e]));
  }
#pragma unroll
  for (int e = 0; e < 8; ++e) L[wg][c8 + e] = m[e];
  __syncthreads();
  const int c = tid;
  float r = L[0][c];
#pragma unroll
  for (int g = 1; g < 8; ++g) r = fmaxf(r, L[g][c]);
  rowp[(((b << 8) | c) << 6) + h] = r;
}

__global__ __launch_bounds__(256)
void poolw_k(const u16* __restrict__ T, float* __restrict__ colp)
{
  __shared__ float L[4][256];
  const int tid = threadIdx.x;
  const int b = blockIdx.x >> 6, w = blockIdx.x & 63;
  const int hs = tid >> 6;             // 0..3 (h substream)
  const int c4 = (tid & 63) * 4;
  const u16* base = T + (((size_t)b * 4096 + w) << 8) + c4;
  float m0 = -3.0e38f, m1 = -3.0e38f, m2 = -3.0e38f, m3 = -3.0e38f;
#pragma unroll
  for (int hi = 0; hi < 16; ++hi){
    int h = hi * 4 + hs;
    u16x4 v = *(const u16x4*)(base + ((size_t)h << 14));
    m0 = fmaxf(m0, h2f(v[0]));
    m1 = fmaxf(m1, h2f(v[1]));
    m2 = fmaxf(m2, h2f(v[2]));
    m3 = fmaxf(m3, h2f(v[3]));
  }
  L[hs][c4 + 0] = m0; L[hs][c4 + 1] = m1; L[hs][c4 + 2] = m2; L[hs][c4 + 3] = m3;
  __syncthreads();
  const int c = tid;
  float r = fmaxf(fmaxf(L[0][c], L[1][c]), fmaxf(L[2][c], L[3][c]));
  colp[(((b << 8) | c) << 6) + w] = r;
}

// ---------------- attention + LN/SiLU; writes transposed fp16 ----------------
__device__ __forceinline__ float ln_silu_wave(float v){
  float mu = wred_sum(v) * (1.f / 64.f);
  float d = v - mu;
  float var = wred_sum(d * d) * (1.f / 64.f);
  float hn = d * rsqrtf(var + 1e-5f);
  return hn / (1.f + __expf(-hn));
}

__global__ void attn_k(const float* __restrict__ qw, const float* __restrict__ kw,
                       const float* __restrict__ qh, const float* __restrict__ kh,
                       u16* __restrict__ xahT, u16* __restrict__ xawT)
{
  int row  = blockIdx.x * 4 + (threadIdx.x >> 6);
  int lane = threadIdx.x & 63;
  int idx  = (row << 6) + lane;
  float qwv = qw[idx], kwv = kw[idx], qhv = qh[idx], khv = kh[idx];
  float Pq = wred_max(qwv), mq = wred_min(qwv);
  float Pk = wred_max(khv), mk = wred_min(khv);
  float aw = fmaxf(kwv * Pq, kwv * mq);
  float ah = fmaxf(qhv * Pk, qhv * mk);
  aw = ln_silu_wave(aw);
  ah = ln_silu_wave(ah);
  int b = row >> 8, q = row & 255;
  xawT[((b * 64 + lane) << 8) + q] = f2h(aw);
  xahT[((b * 64 + lane) << 8) + q] = f2h(ah);
}

// ---------------- weight/param pack (fp16) ----------------
__global__ void pack_k(const float* __restrict__ wqkv, const float* __restrict__ wco,
                       const float* __restrict__ wb1, const float* __restrict__ wb2,
                       const float* gq, const float* bq, const float* mq, const float* vq,
                       const float* gc, const float* bc, const float* mc, const float* vc,
                       const float* g1, const float* b1, const float* m1, const float* v1, const float* bias1,
                       const float* g2, const float* b2, const float* m2, const float* v2, const float* bias2,
                       u16* __restrict__ WQ, u16* __restrict__ WCO, u16* __restrict__ WB1, u16* __restrict__ WB2,
                       float4* __restrict__ PP)
{
  const int E0 = 196608, E1 = 196608 + 1179648, E2 = 196608 + 1179648 + 589824, E3 = 2031616;
  int i = blockIdx.x * 256 + threadIdx.x;
  if (i >= E3 + 1536) return;
  if (i < E0){ WQ[i] = f2h(wqkv[i]); }
  else if (i < E1){
    int d = i - E0; int tap = d / 131072; int rm = d % 131072; int m = rm >> 9; int ci = rm & 511;
    WCO[d] = f2h(wco[(size_t)((m << 9) | ci) * 9 + tap]);
  } else if (i < E2){
    int d = i - E1; int tap = d / 65536; int rm = d & 65535; int m = rm >> 8; int ci = rm & 255;
    WB1[d] = f2h(wb1[(size_t)((m << 8) | ci) * 9 + tap]);
  } else if (i < E3){
    int d = i - E2; WB2[d] = f2h(wb2[d]);
  } else {
    int c = i - E3;
    float g, be, mm, vv, bi;
    if (c < 768){ g = gq[c]; be = bq[c]; mm = mq[c]; vv = vq[c]; bi = 0.f; }
    else if (c < 1024){ int j = c - 768;  g = gc[j]; be = bc[j]; mm = mc[j]; vv = vc[j]; bi = 0.f; }
    else if (c < 1280){ int j = c - 1024; g = g1[j]; be = b1[j]; mm = m1[j]; vv = v1[j]; bi = bias1[j]; }
    else              { int j = c - 1280; g = g2[j]; be = b2[j]; mm = m2[j]; vv = v2[j]; bi = bias2[j]; }
    PP[c] = make_float4(g / sqrtf(vv + 1e-3f), be, mm, bi);
  }
}

// ---------------- launch ----------------
extern "C" void kernel_launch(void* const* d_in, const int* in_sizes, int n_in,
                              void* d_out, int out_size, void* d_ws, size_t ws_size,
                              hipStream_t stream)
{
  const float* x       = (const float*)d_in[0];
  const float* w_qkv   = (const float*)d_in[1];
  const float* g_qkv   = (const float*)d_in[2];
  const float* b_qkv   = (const float*)d_in[3];
  const float* m_qkv   = (const float*)d_in[4];
  const float* v_qkv   = (const float*)d_in[5];
  const float* w_co    = (const float*)d_in[6];
  const float* g_co    = (const float*)d_in[7];
  const float* b_co    = (const float*)d_in[8];
  const float* m_co    = (const float*)d_in[9];
  const float* v_co    = (const float*)d_in[10];
  const float* w_b1    = (const float*)d_in[11];
  const float* bias_b1 = (const float*)d_in[12];
  const float* g_b1    = (const float*)d_in[13];
  const float* b_b1    = (const float*)d_in[14];
  const float* m_b1    = (const float*)d_in[15];
  const float* v_b1    = (const float*)d_in[16];
  const float* w_b2    = (const float*)d_in[17];
  const float* bias_b2 = (const float*)d_in[18];
  const float* g_b2    = (const float*)d_in[19];
  const float* b_b2    = (const float*)d_in[20];
  const float* m_b2    = (const float*)d_in[21];
  const float* v_b2    = (const float*)d_in[22];
  float* out = (float*)d_out;

  // ---- workspace layout (bytes) ----
  char* W = (char*)d_ws;
  u16*    WQ   = (u16*)(W + 0);              // 768*256            -> 393216
  u16*    WCO  = (u16*)(W + 393216);         // 9*256*512          -> 2359296
  u16*    WB1  = (u16*)(W + 2752512);        // 9*256*256          -> 1179648
  u16*    WB2  = (u16*)(W + 3932160);        // 256*256            -> 131072
  float4* PP   = (float4*)(W + 4063232);     // 1536*16            -> 24576
  // Time-shared 33.5 MB slot: TQ (q acts) -> TK (k acts) -> TV (v acts) -> Y2
  u16*    TQK  = (u16*)(W + 4087808);        // 16*4096*256 f16    -> ends 37642240
  u16*    TV   = TQK;
  u16*    XAHT = (u16*)(W + 37642240);       // 16*64*256 f16      -> 524288
  u16*    XAWT = (u16*)(W + 38166528);       //                    -> 524288
  u16*    XH   = (u16*)(W + 38690816);       // x NHWC f16, 33.5MB (dead after conv-v)
  u16*    Y1   = (u16*)(W + 38690816);       // overlays XH (written by G2, after XH dead)
  u16*    Y2   = TV;                          // TV dead after G2
  float*  qh_  = (float*)(W + 72245248);     // 1 MB
  float*  kh_  = (float*)(W + 73293824);     // 1 MB
  float*  qw_  = (float*)(W + 74342400);     // 1 MB
  float*  kw_  = (float*)(W + 75390976);     // 1 MB

  const size_t NEED = 76439552;
  if (ws_size < NEED) return;

  const float SHP_N3 = -3.0f * PI_F * 0.5f;
  const float SHP_1  =  1.0f * PI_F * 0.5f;
  const float SHP_08 =  0.8f * PI_F * 0.5f;

  dim3 blk(256);

  pack_k<<<7942, blk, 0, stream>>>(w_qkv, w_co, w_b1, w_b2,
      g_qkv, b_qkv, m_qkv, v_qkv,
      g_co,  b_co,  m_co,  v_co,
      g_b1,  b_b1,  m_b1,  v_b1,  bias_b1,
      g_b2,  b_b2,  m_b2,  v_b2,  bias_b2,
      WQ, WCO, WB1, WB2, PP);

  // G0: transpose x -> NHWC-256 f16
  xpose_k<<<1024, blk, 0, stream>>>(x, XH);

  // G1-q: qkv conv channels 0..255 (q) -> TQK; then pool
  conv1_res<1><<<256, 512, 0, stream>>>(
      WQ, XH, TQK, nullptr, PP, SHP_N3, 1.3f, 0);
  poolh_k<<<1024, blk, 0, stream>>>(TQK, qh_);
  poolw_k<<<1024, blk, 0, stream>>>(TQK, qw_);

  // G1-k: channels 256..511 (k) -> TQK (TQ dead); then pool
  conv1_res<1><<<256, 512, 0, stream>>>(
      WQ + (size_t)256 * 256, XH, TQK, nullptr, PP + 256, SHP_N3, 1.3f, 0);
  poolh_k<<<1024, blk, 0, stream>>>(TQK, kh_);
  poolw_k<<<1024, blk, 0, stream>>>(TQK, kw_);

  // attention
  attn_k<<<1024, blk, 0, stream>>>(qw_, kw_, qh_, kh_, XAHT, XAWT);

  // G1-v: channels 512..767 (v) -> TV (TK dead)
  conv1_res<1><<<256, 512, 0, stream>>>(
      WQ + (size_t)512 * 256, XH, TV, nullptr, PP + 512, SHP_N3, 1.3f, 0);

  // G2: co 3x3 conv over implicit concat [xa | xv] -> bn -> ssslu(1,0) -> Y1
  conv3_mfma<512, true><<<dim3(256, 2), blk, 0, stream>>>(
      WCO, TV, Y1, PP + 768, XAHT, XAWT, SHP_1, 1.0f, 1);

  // G3: b1 3x3 conv (+bias) -> ssslu(-3,0.3) -> bn -> Y2
  conv3_mfma<256, false><<<dim3(256, 2), blk, 0, stream>>>(
      WB1, Y1, Y2, PP + 1024, nullptr, nullptr, SHP_N3, 1.3f, 0);

  // G4: b2 1x1 conv (+bias) -> bn -> ssslu(0.8,0) -> sigmoid -> out
  conv1_res<2><<<256, 512, 0, stream>>>(
      WB2, Y2, nullptr, out, PP + 1280, SHP_08, 1.0f, 1);
}

// Round 10
// 368.535 us; speedup vs baseline: 1.6504x; 1.0634x over previous
//
#include <hip/hip_runtime.h>
#include <hip/hip_bf16.h>
#include <math.h>

#define PI_F 3.14159265358979323846f

typedef unsigned short u16;
typedef unsigned int   u32;
typedef float    f32x4 __attribute__((ext_vector_type(4)));
typedef _Float16 f16x8 __attribute__((ext_vector_type(8)));
typedef u16      u16x8 __attribute__((ext_vector_type(8)));
typedef u16      u16x4 __attribute__((ext_vector_type(4)));

__device__ __forceinline__ u16 f2h(float f){ union{ _Float16 h; u16 u; } c; c.h = (_Float16)f; return c.u; }
__device__ __forceinline__ float h2f(u16 u){ union{ u16 u; _Float16 h; } c; c.u = u; return (float)c.h; }

__device__ __forceinline__ void gl16(const void* g, void* l){
  __builtin_amdgcn_global_load_lds((const __attribute__((address_space(1))) u32*)g,
                                   (__attribute__((address_space(3))) u32*)l, 16, 0, 0);
}

__device__ __forceinline__ int SWZ(int r){ return (r>>1)&3; }

__device__ __forceinline__ float wred_max(float v){
#pragma unroll
  for (int m = 32; m; m >>= 1) v = fmaxf(v, __shfl_xor(v, m));
  return v;
}
__device__ __forceinline__ float wred_min(float v){
#pragma unroll
  for (int m = 32; m; m >>= 1) v = fminf(v, __shfl_xor(v, m));
  return v;
}
__device__ __forceinline__ float wred_sum(float v){
#pragma unroll
  for (int m = 32; m; m >>= 1) v += __shfl_xor(v, m);
  return v;
}

__device__ __forceinline__ float ssslu_f(float x, float shp, float bp1){
  float s = x / (1.0f + fabsf(x));
  return x * (__sinf(s * shp) + bp1);
}

__device__ __forceinline__ float epi_val(float v, float4 p, float shp, float bp1, int ORDER, bool SIG){
  v += p.w;  // bias
  if (ORDER == 0){ v = ssslu_f(v, shp, bp1); v = (v - p.z) * p.x + p.y; }
  else           { v = (v - p.z) * p.x + p.y; v = ssslu_f(v, shp, bp1); }
  if (SIG) v = 1.f / (1.f + __expf(-v));
  return v;
}

__device__ __forceinline__ f16x8 mul8h(u16x8 a, u16x8 b){
  union{ u16x8 u; f16x8 h; } A, B; A.u = a; B.u = b;
  return A.h * B.h;
}

// =====================================================================
// x transpose: NCHW fp32 -> NHWC-256 f16 (XH). One (b,h) plane per block.
// =====================================================================
__global__ __launch_bounds__(256)
void xpose_k(const float* __restrict__ X, u16* __restrict__ XH)
{
  __shared__ u16 L[16384];   // 32 KB
  const int tid = threadIdx.x;
  const int b = blockIdx.x >> 6, h = blockIdx.x & 63;
  const float* xp = X + (size_t)b * 256 * 4096 + h * 64;
#pragma unroll
  for (int i = 0; i < 16; ++i){
    int ci = i * 16 + (tid >> 4);
    int w4 = (tid & 15) * 4;
    float4 v = *(const float4*)(xp + (size_t)ci * 4096 + w4);
    int sw = 4 * ((ci >> 3) & 15);
    u16x4 d;
    d[0] = f2h(v.x); d[1] = f2h(v.y); d[2] = f2h(v.z); d[3] = f2h(v.w);
    *(u16x4*)&L[ci * 64 + (w4 ^ sw)] = d;
  }
  __syncthreads();
  u16* out = XH + (((size_t)b * 4096 + (size_t)h * 64) << 8);
#pragma unroll
  for (int it = 0; it < 8; ++it){
    int w   = it * 8 + (tid >> 5);
    int m   = tid & 31;
    int ci0 = m * 8;
    int base = (w & ~3) ^ (4 * (m & 15));
    int wl   = w & 3;
    u16x8 o;
#pragma unroll
    for (int k = 0; k < 8; ++k)
      o[k] = L[(ci0 + k) * 64 + base + wl];
    *(u16x8*)&out[w * 256 + ci0] = o;
  }
}

// =====================================================================
// 3x3 conv, BM=128, BN=256 (4 h x 64 w), 256 thr / 4 waves, 2 blocks/CU.
// Round-7 version (VALU-lean, gl16 STAGE_B at d==0): best measured.
// =====================================================================
template<int CI_T, bool CAT>
__global__ __launch_bounds__(256, 2)
void conv3_mfma(const u16* __restrict__ Apk, const u16* __restrict__ Bg,
                u16* __restrict__ DstH, const float4* __restrict__ pp,
                const u16* __restrict__ xahT_, const u16* __restrict__ xawT_,
                float shp, float bp1, int ORDER)
{
  constexpr int NCC = CI_T / 32;
  constexpr int NIT = NCC * 3;
  __shared__ __align__(16) u16 sAB[37248];   // 74496 B -> 2 blocks/CU

  const int tid  = threadIdx.x;
  const int lane = tid & 63;
  const int wv   = tid >> 6;        // 0..3
  const int wn   = wv;              // h row within quad
  const int l15  = lane & 15, l4 = lane >> 4;

  const int bx  = blockIdx.x;
  const int bid = (bx & 7) * 32 + (bx >> 3);   // bijective XCD swizzle (256 % 8 == 0)
  const int b   = bid >> 4;
  const int r0  = (bid & 15) * 4;              // output rows r0..r0+3
  const int m0  = blockIdx.y * 128;            // co half

  if (tid < 192){
    int rr = tid >> 5, rem = tid & 31;
    int wp = (rem & 16) ? 65 : 0;
    *(u32*)&sAB[24576 + rr * 2112 + wp * 32 + (rem & 15) * 2] = 0;
  }
  if (r0 == 0)
    for (int i = tid; i < 1056; i += 256) *(u32*)&sAB[24576 + i * 2] = 0;
  if (r0 == 60)
    for (int i = tid; i < 1056; i += 256) *(u32*)&sAB[24576 + 5 * 2112 + i * 2] = 0;

  const int rA = tid >> 2, s4 = tid & 3;
  const u32 offA0 = ((u32)rA * CI_T + ((s4 ^ SWZ(rA)) << 3)) * 2;
  const u32 offA1 = ((u32)(rA + 64) * CI_T + ((s4 ^ SWZ(rA + 64)) << 3)) * 2;
  const u32 offB  = (((u32)rA << 8) + ((s4 ^ SWZ(rA + 1)) << 3)) * 2;   // rA doubles as w

  auto STAGE_A = [&](int it2){
    int d2 = it2 % 3, c2 = it2 / 3;
    u16* dst = &sAB[(it2 & 1) * 12288 + wv * 512];
    const char* pa = (const char*)(Apk + ((size_t)(d2 * 3 * 256) + m0) * CI_T + c2 * 32);
#pragma unroll
    for (int j2 = 0; j2 < 3; ++j2){
      gl16(pa + offA0, dst + j2 * 4096);
      gl16(pa + offA1, dst + j2 * 4096 + 2048);
      pa += (size_t)256 * CI_T * 2;
    }
  };
  auto STAGE_B = [&](int c2){
#pragma unroll
    for (int j = 0; j < 6; ++j){
      int hh = r0 - 1 + j;
      if ((unsigned)hh >= 64u) continue;
      if (CAT && c2 < 8){
        int w = rA, s = s4;
        int ci0 = c2 * 32 + ((s ^ SWZ(w + 1)) << 3);
        u16x8 vh = *(const u16x8*)&xahT_[((b * 64 + hh) << 8) + ci0];
        u16x8 vw = *(const u16x8*)&xawT_[((b * 64 + w ) << 8) + ci0];
        *(f16x8*)&sAB[24576 + j * 2112 + (w + 1) * 32 + s * 8] = mul8h(vh, vw);
      } else {
        int cio = CAT ? (c2 * 32 - 256) : (c2 * 32);
        const char* pb = (const char*)(Bg + (((size_t)b * 4096 + (size_t)hh * 64) << 8) + cio);
        gl16(pb + offB, &sAB[24576 + j * 2112 + 32 + wv * 512]);
      }
    }
  };

  f32x4 acc[8][4];
#pragma unroll
  for (int i = 0; i < 8; ++i)
#pragma unroll
    for (int j = 0; j < 4; ++j){ acc[i][j][0]=0.f; acc[i][j][1]=0.f; acc[i][j][2]=0.f; acc[i][j][3]=0.f; }

  const char* lds = (const char*)sAB;
  const u32 aoff = (u32)l15 * 64 + (u32)((l4 ^ ((l15 >> 1) & 3)) << 4);
  const char* ab0 = lds + aoff;
  const char* ab1 = lds + aoff + 24576;
  const u32 bcom = 49152u + (u32)wn * 4224;
  const char* bb0 = lds + bcom + (u32)(l15 + 0) * 64 + (u32)((l4 ^ (((l15 + 0) >> 1) & 3)) << 4);
  const char* bb1 = lds + bcom + (u32)(l15 + 1) * 64 + (u32)((l4 ^ (((l15 + 1) >> 1) & 3)) << 4);
  const char* bb2 = lds + bcom + (u32)(l15 + 2) * 64 + (u32)((l4 ^ (((l15 + 2) >> 1) & 3)) << 4);

  STAGE_A(0);

  for (int c = 0; c < NCC; ++c){
#pragma unroll
    for (int d = 0; d < 3; ++d){
      const int it = 3 * c + d;
      if (it + 1 < NIT) STAGE_A(it + 1);
      if (d == 0){ STAGE_B(c); __syncthreads(); }

      const char* ab = ((c + d) & 1) ? ab1 : ab0;
#pragma unroll
      for (int dw = 0; dw < 3; ++dw){
        const char* bp = (dw == 0) ? bb0 : (dw == 1) ? bb1 : bb2;
        f16x8 afr[8], bfr[4];
#pragma unroll
        for (int fm = 0; fm < 8; ++fm)
          afr[fm] = *(const f16x8*)(ab + dw * 8192 + fm * 1024);
#pragma unroll
        for (int fn = 0; fn < 4; ++fn)
          bfr[fn] = *(const f16x8*)(bp + d * 4224 + fn * 1024);
        __builtin_amdgcn_s_setprio(1);
#pragma unroll
        for (int fm = 0; fm < 8; ++fm)
#pragma unroll
          for (int fn = 0; fn < 4; ++fn)
            acc[fm][fn] = __builtin_amdgcn_mfma_f32_16x16x32_f16(afr[fm], bfr[fn], acc[fm][fn], 0, 0, 0);
        __builtin_amdgcn_s_setprio(0);
      }
      __syncthreads();
    }
  }

  const int h = r0 + wn;
#pragma unroll
  for (int fm = 0; fm < 8; ++fm){
    const int cobase = m0 + fm * 16 + 4 * l4;
    float4 P0 = pp[cobase], P1 = pp[cobase+1], P2 = pp[cobase+2], P3 = pp[cobase+3];
#pragma unroll
    for (int fn = 0; fn < 4; ++fn){
      int w = fn * 16 + l15;
      float v0 = epi_val(acc[fm][fn][0], P0, shp, bp1, ORDER, false);
      float v1 = epi_val(acc[fm][fn][1], P1, shp, bp1, ORDER, false);
      float v2 = epi_val(acc[fm][fn][2], P2, shp, bp1, ORDER, false);
      float v3 = epi_val(acc[fm][fn][3], P3, shp, bp1, ORDER, false);
      uint2 st;
      st.x = (u32)f2h(v0) | ((u32)f2h(v1) << 16);
      st.y = (u32)f2h(v2) | ((u32)f2h(v3) << 16);
      *(uint2*)&DstH[(((size_t)b * 4096 + (size_t)h * 64 + w) << 8) + cobase] = st;
    }
  }
}

// =====================================================================
// 1x1 conv, A-RESIDENT + barrier-free K-loop (round-7 depth-1 prefetch).
// EPI: 1 = NHWC f16 store, 2 = NCHW fp32 + sigmoid (d_out),
//      3 = NHWC f16 store + FUSED row-max (max over w -> rowp[b,c,h]).
// Row-max is per-wave (3 fmax + 4 shfl per 4 co) — no cross-wave
// serialization (the round-5 trap was the col-max tournament only).
// =====================================================================
template<int EPI>
__global__ __launch_bounds__(512, 2)
void conv1_res(const u16* __restrict__ Apk, const u16* __restrict__ Bg,
               u16* __restrict__ DstH, float* __restrict__ DstF,
               const float4* __restrict__ pp,
               float* __restrict__ rowp,
               float shp, float bp1, int ORDER)
{
  __shared__ __align__(16) u16 AL[65536];   // [8 c][256 m][32 ci] swizzled = 128 KB

  const int tid  = threadIdx.x;
  const int lane = tid & 63;
  const int wv   = tid >> 6;        // 0..7
  const int wm   = wv >> 2;         // 0..1 (M half: 128 co)
  const int wn   = wv & 3;          // 0..3 (h row)
  const int l15  = lane & 15, l4 = lane >> 4;

  const int bx   = blockIdx.x;
  const int bid  = (bx & 7) * 32 + (bx >> 3);  // bijective XCD swizzle (256 % 8 == 0)
  const int b    = bid >> 4;
  const int h0   = (bid & 15) * 4;

  {
    const int g0 = tid;
    const int g1 = 512 + tid;
    const int mA0 = g0 >> 2, sA0 = g0 & 3;
    const int mA1 = g1 >> 2, sA1 = g1 & 3;
    const u32 offA0 = ((u32)mA0 * 256 + ((sA0 ^ SWZ(mA0)) << 3)) * 2;
    const u32 offA1 = ((u32)mA1 * 256 + ((sA1 ^ SWZ(mA1)) << 3)) * 2;
#pragma unroll
    for (int c = 0; c < 8; ++c){
      const char* pa = (const char*)(Apk + c * 32);
      gl16(pa + offA0, &AL[c * 8192 + (wv * 64) * 8]);
      gl16(pa + offA1, &AL[c * 8192 + (512 + wv * 64) * 8]);
    }
  }

  const u16* Bp = Bg + (((size_t)b * 4096 + (size_t)(h0 + wn) * 64) << 8) + (l15 << 8) + (l4 << 3);
#define LDB(c, fn) (*(const f16x8*)(Bp + ((fn) * 16 << 8) + (c) * 32))

  f32x4 acc[8][4];
#pragma unroll
  for (int i = 0; i < 8; ++i)
#pragma unroll
    for (int j = 0; j < 4; ++j){ acc[i][j][0]=0.f; acc[i][j][1]=0.f; acc[i][j][2]=0.f; acc[i][j][3]=0.f; }

  f16x8 bn0 = LDB(0, 0), bn1 = LDB(0, 1), bn2 = LDB(0, 2), bn3 = LDB(0, 3);

  __syncthreads();   // the ONLY barrier: A resident from here on

  const char* abase = (const char*)AL + wm * 8192 + l15 * 64 + ((l4 ^ SWZ(l15)) << 4);

#pragma unroll
  for (int c = 0; c < 8; ++c){
    f16x8 b0 = bn0, b1 = bn1, b2 = bn2, b3 = bn3;
    if (c < 7){
      bn0 = LDB(c + 1, 0); bn1 = LDB(c + 1, 1); bn2 = LDB(c + 1, 2); bn3 = LDB(c + 1, 3);
    }
    f16x8 afr[8];
#pragma unroll
    for (int fm = 0; fm < 8; ++fm)
      afr[fm] = *(const f16x8*)(abase + c * 16384 + fm * 1024);
    __builtin_amdgcn_s_setprio(1);
#pragma unroll
    for (int fm = 0; fm < 8; ++fm){
      acc[fm][0] = __builtin_amdgcn_mfma_f32_16x16x32_f16(afr[fm], b0, acc[fm][0], 0, 0, 0);
      acc[fm][1] = __builtin_amdgcn_mfma_f32_16x16x32_f16(afr[fm], b1, acc[fm][1], 0, 0, 0);
      acc[fm][2] = __builtin_amdgcn_mfma_f32_16x16x32_f16(afr[fm], b2, acc[fm][2], 0, 0, 0);
      acc[fm][3] = __builtin_amdgcn_mfma_f32_16x16x32_f16(afr[fm], b3, acc[fm][3], 0, 0, 0);
    }
    __builtin_amdgcn_s_setprio(0);
  }
#undef LDB

  const int h = h0 + wn;
#pragma unroll
  for (int fm = 0; fm < 8; ++fm){
    const int cobase = wm * 128 + fm * 16 + 4 * l4;
    float4 P0 = pp[cobase], P1 = pp[cobase+1], P2 = pp[cobase+2], P3 = pp[cobase+3];
    if (EPI == 2){
#pragma unroll
      for (int fn = 0; fn < 4; ++fn){
        int w = fn * 16 + l15;
        float v0 = epi_val(acc[fm][fn][0], P0, shp, bp1, ORDER, true);
        float v1 = epi_val(acc[fm][fn][1], P1, shp, bp1, ORDER, true);
        float v2 = epi_val(acc[fm][fn][2], P2, shp, bp1, ORDER, true);
        float v3 = epi_val(acc[fm][fn][3], P3, shp, bp1, ORDER, true);
        size_t base = ((size_t)(b * 256 + cobase)) * 4096 + (size_t)h * 64 + w;
        DstF[base]          = v0;
        DstF[base + 4096]   = v1;
        DstF[base + 2*4096] = v2;
        DstF[base + 3*4096] = v3;
      }
    } else {
      float ev[4][4];
#pragma unroll
      for (int fn = 0; fn < 4; ++fn){
        ev[fn][0] = epi_val(acc[fm][fn][0], P0, shp, bp1, ORDER, false);
        ev[fn][1] = epi_val(acc[fm][fn][1], P1, shp, bp1, ORDER, false);
        ev[fn][2] = epi_val(acc[fm][fn][2], P2, shp, bp1, ORDER, false);
        ev[fn][3] = epi_val(acc[fm][fn][3], P3, shp, bp1, ORDER, false);
        int w = fn * 16 + l15;
        uint2 st;
        st.x = (u32)f2h(ev[fn][0]) | ((u32)f2h(ev[fn][1]) << 16);
        st.y = (u32)f2h(ev[fn][2]) | ((u32)f2h(ev[fn][3]) << 16);
        *(uint2*)&DstH[(((size_t)b * 4096 + (size_t)h * 64 + w) << 8) + cobase] = st;
      }
      if (EPI == 3){
#pragma unroll
        for (int r = 0; r < 4; ++r){
          float mv = fmaxf(fmaxf(ev[0][r], ev[1][r]), fmaxf(ev[2][r], ev[3][r]));
          mv = fmaxf(mv, __shfl_xor(mv, 1));
          mv = fmaxf(mv, __shfl_xor(mv, 2));
          mv = fmaxf(mv, __shfl_xor(mv, 4));
          mv = fmaxf(mv, __shfl_xor(mv, 8));
          if (l15 == 0)
            rowp[(((b << 8) | (cobase + r)) << 6) + h] = mv;
        }
      }
    }
  }
}

// =====================================================================
// poolw: colp[b,c,w] = max_h T   — one (b,w) column per block.
// (poolh removed: row-max fused into conv1_res<3>.)
// =====================================================================
__global__ __launch_bounds__(256)
void poolw_k(const u16* __restrict__ T, float* __restrict__ colp)
{
  __shared__ float L[4][256];
  const int tid = threadIdx.x;
  const int b = blockIdx.x >> 6, w = blockIdx.x & 63;
  const int hs = tid >> 6;             // 0..3 (h substream)
  const int c4 = (tid & 63) * 4;
  const u16* base = T + (((size_t)b * 4096 + w) << 8) + c4;
  float m0 = -3.0e38f, m1 = -3.0e38f, m2 = -3.0e38f, m3 = -3.0e38f;
#pragma unroll
  for (int hi = 0; hi < 16; ++hi){
    int h = hi * 4 + hs;
    u16x4 v = *(const u16x4*)(base + ((size_t)h << 14));
    m0 = fmaxf(m0, h2f(v[0]));
    m1 = fmaxf(m1, h2f(v[1]));
    m2 = fmaxf(m2, h2f(v[2]));
    m3 = fmaxf(m3, h2f(v[3]));
  }
  L[hs][c4 + 0] = m0; L[hs][c4 + 1] = m1; L[hs][c4 + 2] = m2; L[hs][c4 + 3] = m3;
  __syncthreads();
  const int c = tid;
  float r = fmaxf(fmaxf(L[0][c], L[1][c]), fmaxf(L[2][c], L[3][c]));
  colp[(((b << 8) | c) << 6) + w] = r;
}

// ---------------- attention + LN/SiLU; writes transposed fp16 ----------------
__device__ __forceinline__ float ln_silu_wave(float v){
  float mu = wred_sum(v) * (1.f / 64.f);
  float d = v - mu;
  float var = wred_sum(d * d) * (1.f / 64.f);
  float hn = d * rsqrtf(var + 1e-5f);
  return hn / (1.f + __expf(-hn));
}

__global__ void attn_k(const float* __restrict__ qw, const float* __restrict__ kw,
                       const float* __restrict__ qh, const float* __restrict__ kh,
                       u16* __restrict__ xahT, u16* __restrict__ xawT)
{
  int row  = blockIdx.x * 4 + (threadIdx.x >> 6);
  int lane = threadIdx.x & 63;
  int idx  = (row << 6) + lane;
  float qwv = qw[idx], kwv = kw[idx], qhv = qh[idx], khv = kh[idx];
  float Pq = wred_max(qwv), mq = wred_min(qwv);
  float Pk = wred_max(khv), mk = wred_min(khv);
  float aw = fmaxf(kwv * Pq, kwv * mq);
  float ah = fmaxf(qhv * Pk, qhv * mk);
  aw = ln_silu_wave(aw);
  ah = ln_silu_wave(ah);
  int b = row >> 8, q = row & 255;
  xawT[((b * 64 + lane) << 8) + q] = f2h(aw);
  xahT[((b * 64 + lane) << 8) + q] = f2h(ah);
}

// ---------------- weight/param pack (fp16) ----------------
__global__ void pack_k(const float* __restrict__ wqkv, const float* __restrict__ wco,
                       const float* __restrict__ wb1, const float* __restrict__ wb2,
                       const float* gq, const float* bq, const float* mq, const float* vq,
                       const float* gc, const float* bc, const float* mc, const float* vc,
                       const float* g1, const float* b1, const float* m1, const float* v1, const float* bias1,
                       const float* g2, const float* b2, const float* m2, const float* v2, const float* bias2,
                       u16* __restrict__ WQ, u16* __restrict__ WCO, u16* __restrict__ WB1, u16* __restrict__ WB2,
                       float4* __restrict__ PP)
{
  const int E0 = 196608, E1 = 196608 + 1179648, E2 = 196608 + 1179648 + 589824, E3 = 2031616;
  int i = blockIdx.x * 256 + threadIdx.x;
  if (i >= E3 + 1536) return;
  if (i < E0){ WQ[i] = f2h(wqkv[i]); }
  else if (i < E1){
    int d = i - E0; int tap = d / 131072; int rm = d % 131072; int m = rm >> 9; int ci = rm & 511;
    WCO[d] = f2h(wco[(size_t)((m << 9) | ci) * 9 + tap]);
  } else if (i < E2){
    int d = i - E1; int tap = d / 65536; int rm = d & 65535; int m = rm >> 8; int ci = rm & 255;
    WB1[d] = f2h(wb1[(size_t)((m << 8) | ci) * 9 + tap]);
  } else if (i < E3){
    int d = i - E2; WB2[d] = f2h(wb2[d]);
  } else {
    int c = i - E3;
    float g, be, mm, vv, bi;
    if (c < 768){ g = gq[c]; be = bq[c]; mm = mq[c]; vv = vq[c]; bi = 0.f; }
    else if (c < 1024){ int j = c - 768;  g = gc[j]; be = bc[j]; mm = mc[j]; vv = vc[j]; bi = 0.f; }
    else if (c < 1280){ int j = c - 1024; g = g1[j]; be = b1[j]; mm = m1[j]; vv = v1[j]; bi = bias1[j]; }
    else              { int j = c - 1280; g = g2[j]; be = b2[j]; mm = m2[j]; vv = v2[j]; bi = bias2[j]; }
    PP[c] = make_float4(g / sqrtf(vv + 1e-3f), be, mm, bi);
  }
}

// ---------------- launch ----------------
extern "C" void kernel_launch(void* const* d_in, const int* in_sizes, int n_in,
                              void* d_out, int out_size, void* d_ws, size_t ws_size,
                              hipStream_t stream)
{
  const float* x       = (const float*)d_in[0];
  const float* w_qkv   = (const float*)d_in[1];
  const float* g_qkv   = (const float*)d_in[2];
  const float* b_qkv   = (const float*)d_in[3];
  const float* m_qkv   = (const float*)d_in[4];
  const float* v_qkv   = (const float*)d_in[5];
  const float* w_co    = (const float*)d_in[6];
  const float* g_co    = (const float*)d_in[7];
  const float* b_co    = (const float*)d_in[8];
  const float* m_co    = (const float*)d_in[9];
  const float* v_co    = (const float*)d_in[10];
  const float* w_b1    = (const float*)d_in[11];
  const float* bias_b1 = (const float*)d_in[12];
  const float* g_b1    = (const float*)d_in[13];
  const float* b_b1    = (const float*)d_in[14];
  const float* m_b1    = (const float*)d_in[15];
  const float* v_b1    = (const float*)d_in[16];
  const float* w_b2    = (const float*)d_in[17];
  const float* bias_b2 = (const float*)d_in[18];
  const float* g_b2    = (const float*)d_in[19];
  const float* b_b2    = (const float*)d_in[20];
  const float* m_b2    = (const float*)d_in[21];
  const float* v_b2    = (const float*)d_in[22];
  float* out = (float*)d_out;

  // ---- workspace layout (bytes) ----
  char* W = (char*)d_ws;
  u16*    WQ   = (u16*)(W + 0);              // 768*256            -> 393216
  u16*    WCO  = (u16*)(W + 393216);         // 9*256*512          -> 2359296
  u16*    WB1  = (u16*)(W + 2752512);        // 9*256*256          -> 1179648
  u16*    WB2  = (u16*)(W + 3932160);        // 256*256            -> 131072
  float4* PP   = (float4*)(W + 4063232);     // 1536*16            -> 24576
  // Time-shared 33.5 MB slot: TQ (q acts) -> TK (k acts) -> TV (v acts) -> Y2
  u16*    TQK  = (u16*)(W + 4087808);        // 16*4096*256 f16    -> ends 37642240
  u16*    TV   = TQK;
  u16*    XAHT = (u16*)(W + 37642240);       // 16*64*256 f16      -> 524288
  u16*    XAWT = (u16*)(W + 38166528);       //                    -> 524288
  u16*    XH   = (u16*)(W + 38690816);       // x NHWC f16, 33.5MB (dead after conv-v)
  u16*    Y1   = (u16*)(W + 38690816);       // overlays XH (written by G2, after XH dead)
  u16*    Y2   = TV;                          // TV dead after G2
  float*  qh_  = (float*)(W + 72245248);     // 1 MB
  float*  kh_  = (float*)(W + 73293824);     // 1 MB
  float*  qw_  = (float*)(W + 74342400);     // 1 MB
  float*  kw_  = (float*)(W + 75390976);     // 1 MB

  const size_t NEED = 76439552;
  if (ws_size < NEED) return;

  const float SHP_N3 = -3.0f * PI_F * 0.5f;
  const float SHP_1  =  1.0f * PI_F * 0.5f;
  const float SHP_08 =  0.8f * PI_F * 0.5f;

  dim3 blk(256);

  pack_k<<<7942, blk, 0, stream>>>(w_qkv, w_co, w_b1, w_b2,
      g_qkv, b_qkv, m_qkv, v_qkv,
      g_co,  b_co,  m_co,  v_co,
      g_b1,  b_b1,  m_b1,  v_b1,  bias_b1,
      g_b2,  b_b2,  m_b2,  v_b2,  bias_b2,
      WQ, WCO, WB1, WB2, PP);

  // G0: transpose x -> NHWC-256 f16
  xpose_k<<<1024, blk, 0, stream>>>(x, XH);

  // G1-q: qkv conv channels 0..255 (q) -> TQK, fused row-max -> qh_; then col pool
  conv1_res<3><<<256, 512, 0, stream>>>(
      WQ, XH, TQK, nullptr, PP, qh_, SHP_N3, 1.3f, 0);
  poolw_k<<<1024, blk, 0, stream>>>(TQK, qw_);

  // G1-k: channels 256..511 (k) -> TQK (TQ dead), fused row-max -> kh_; col pool
  conv1_res<3><<<256, 512, 0, stream>>>(
      WQ + (size_t)256 * 256, XH, TQK, nullptr, PP + 256, kh_, SHP_N3, 1.3f, 0);
  poolw_k<<<1024, blk, 0, stream>>>(TQK, kw_);

  // attention
  attn_k<<<1024, blk, 0, stream>>>(qw_, kw_, qh_, kh_, XAHT, XAWT);

  // G1-v: channels 512..767 (v) -> TV (TK dead)
  conv1_res<1><<<256, 512, 0, stream>>>(
      WQ + (size_t)512 * 256, XH, TV, nullptr, PP + 512, nullptr, SHP_N3, 1.3f, 0);

  // G2: co 3x3 conv over implicit concat [xa | xv] -> bn -> ssslu(1,0) -> Y1
  conv3_mfma<512, true><<<dim3(256, 2), blk, 0, stream>>>(
      WCO, TV, Y1, PP + 768, XAHT, XAWT, SHP_1, 1.0f, 1);

  // G3: b1 3x3 conv (+bias) -> ssslu(-3,0.3) -> bn -> Y2
  conv3_mfma<256, false><<<dim3(256, 2), blk, 0, stream>>>(
      WB1, Y1, Y2, PP + 1024, nullptr, nullptr, SHP_N3, 1.3f, 0);

  // G4: b2 1x1 conv (+bias) -> bn -> ssslu(0.8,0) -> sigmoid -> out
  conv1_res<2><<<256, 512, 0, stream>>>(
      WB2, Y2, nullptr, out, PP + 1280, nullptr, SHP_08, 1.0f, 1);
}